// Round 4
// baseline (161.366 us; speedup 1.0000x reference)
//
#include <hip/hip_runtime.h>
#include <math.h>

// LinearAttention: B=16, C=256, H=W=64 (N=4096), 8 heads x 32 dim.
// R1: k_fold -> block-per-(b,h) LDS kernel (was 114us latency-bound).
// R2: k_ctxpart -> MFMA fragments straight from global; q-softmax fused
//     into the qkv GEMM epilogue.
// R3: k_xconv pre-pass writes xnbT[n][c] = bf16(x*rinv) transposed (rinv
//     folded into x); GEMM staging becomes pure uint4 loads (was 16 scalar
//     fp32 loads + 16 f2bf per thread per K-step -> VALUBusy 54%).
//     q written transposed qT[n][d] so k_final B-staging is uint4 too.
//     qT aliases the kv buffer (kv dead after ctxpart) to stay <=105.6MB ws.

#define B_ 16
#define C_ 256
#define N_ 4096
#define SCALE_ 0.17677669529663687f
#define EPS_ 1e-12f

typedef __attribute__((ext_vector_type(8))) short bf16x8;
typedef __attribute__((ext_vector_type(4))) float f32x4;

__device__ __forceinline__ ushort f2bf(float f) {
    union { float f; uint u; } x; x.f = f;
    uint r = (x.u + 0x7FFFu + ((x.u >> 16) & 1u)) >> 16;
    return (ushort)r;
}
__device__ __forceinline__ float bf2f(ushort s) {
    union { uint u; float f; } x; x.u = ((uint)s) << 16;
    return x.f;
}

// ---------------- K1: W' = w_qkv * g1 -> bf16 ----------------
__global__ __launch_bounds__(256) void k_prep(const float* __restrict__ w_qkv,
                                              const float* __restrict__ g1,
                                              ushort* __restrict__ Wp) {
    int o = blockIdx.x, c = threadIdx.x;
    Wp[(size_t)o * 256 + c] = f2bf(w_qkv[(size_t)o * 256 + c] * g1[c]);
}

// ---------------- K2: xnbT[b][n][c] = bf16(x[b][c][n] * rinv[b][n]) -------
// block per (64-col n-tile, b); LDS transpose; rinv computed in-block.
__global__ __launch_bounds__(256) void k_xconv(const float* __restrict__ x,
                                               ushort* __restrict__ xnbT) {
    __shared__ float ssp[4][64];
    __shared__ float rinv_s[64];
    __shared__ ushort T[64][268];   // row stride 536B: 8B-aligned, 4-way-ish banks
    int b = blockIdx.y, n0 = blockIdx.x * 64;
    const float* xb = x + (size_t)b * C_ * N_ + n0;
    int t = threadIdx.x;
    int nl = t & 63, cg = t >> 6;    // cg: 0..3, 64 channels each
    float ss = 0.f;
    #pragma unroll 8
    for (int i = 0; i < 64; ++i) {
        float v = xb[(size_t)(cg * 64 + i) * N_ + nl];
        ss += v * v;
    }
    ssp[cg][nl] = ss;
    __syncthreads();
    if (t < 64)
        rinv_s[t] = 16.f / fmaxf(sqrtf(ssp[0][t] + ssp[1][t] + ssp[2][t] + ssp[3][t]), EPS_);
    __syncthreads();
    float rv = rinv_s[nl];
    #pragma unroll 8
    for (int i = 0; i < 64; ++i) {
        int c = cg * 64 + i;
        T[nl][c] = f2bf(xb[(size_t)c * N_ + nl] * rv);   // L2-hot re-read
    }
    __syncthreads();
    int j = t >> 2, ch = t & 3;
    ushort* orow = xnbT + ((size_t)b * N_ + n0 + j) * 256 + ch * 64;
    #pragma unroll
    for (int i = 0; i < 8; ++i)
        *(uint2*)&orow[i * 8] = *(const uint2*)&T[j][ch * 64 + i * 8],
        *(uint2*)&orow[i * 8 + 4] = *(const uint2*)&T[j][ch * 64 + i * 8 + 4];
}

// ---------------- K3: GEMM  C = Wp[rows] @ xn  (both bf16 row-major) ------
// tile 128x128, BK=32, 4 waves each 64x64 via 16x16x32 MFMA.
// qmode=0: rows 256..767 -> kv[d][n] layout.
// qmode=1: rows 0..255 -> per-head softmax over d -> qT[n][d] layout.
__global__ __launch_bounds__(256) void k_gemm(const ushort* __restrict__ Wp,
                                              const ushort* __restrict__ xnbT,
                                              ushort* __restrict__ kvOut,
                                              ushort* __restrict__ qTOut,
                                              int qmode) {
    __shared__ ushort Asub[128][40];
    __shared__ ushort Bsub[128][40];
    const int b = blockIdx.z;
    const int wrow0 = (qmode ? 0 : 256) + blockIdx.y * 128;
    const int col0 = blockIdx.x * 128;
    const int t = threadIdx.x;
    const int l = t & 63, w = t >> 6;
    const int wr = w >> 1, wc = w & 1, grp = l >> 4;
    const ushort* xb = xnbT + (size_t)b * N_ * 256;
    f32x4 acc[4][4] = {};

    for (int k0 = 0; k0 < 256; k0 += 32) {
        int r = t >> 1, ko = (t & 1) * 16;
        const uint4* sa = (const uint4*)(Wp + (size_t)(wrow0 + r) * 256 + k0 + ko);
        *(uint4*)&Asub[r][ko]     = sa[0];
        *(uint4*)&Asub[r][ko + 8] = sa[1];
        const uint4* sb = (const uint4*)(xb + (size_t)(col0 + r) * 256 + k0 + ko);
        *(uint4*)&Bsub[r][ko]     = sb[0];
        *(uint4*)&Bsub[r][ko + 8] = sb[1];
        __syncthreads();
        bf16x8 af[4], bfv[4];
        #pragma unroll
        for (int m = 0; m < 4; ++m)
            af[m] = *(const bf16x8*)&Asub[wr * 64 + m * 16 + (l & 15)][grp * 8];
        #pragma unroll
        for (int n = 0; n < 4; ++n)
            bfv[n] = *(const bf16x8*)&Bsub[wc * 64 + n * 16 + (l & 15)][grp * 8];
        #pragma unroll
        for (int m = 0; m < 4; ++m)
            #pragma unroll
            for (int n = 0; n < 4; ++n)
                acc[m][n] = __builtin_amdgcn_mfma_f32_16x16x32_bf16(af[m], bfv[n], acc[m][n], 0, 0, 0);
        __syncthreads();
    }

    if (qmode) {
        ushort* qTb = qTOut + (size_t)b * N_ * 256;
        #pragma unroll
        for (int n = 0; n < 4; ++n) {
            int cg = col0 + wc * 64 + n * 16 + (l & 15);
            float f[4][4];
            #pragma unroll
            for (int m = 0; m < 4; ++m)
                #pragma unroll
                for (int r = 0; r < 4; ++r) f[m][r] = acc[m][n][r];
            // m=0,1 -> one head (32 d), m=2,3 -> next head
            float mxA = -1e30f, mxB = -1e30f;
            #pragma unroll
            for (int r = 0; r < 4; ++r) {
                mxA = fmaxf(mxA, fmaxf(f[0][r], f[1][r]));
                mxB = fmaxf(mxB, fmaxf(f[2][r], f[3][r]));
            }
            mxA = fmaxf(mxA, __shfl_xor(mxA, 16));
            mxA = fmaxf(mxA, __shfl_xor(mxA, 32));
            mxB = fmaxf(mxB, __shfl_xor(mxB, 16));
            mxB = fmaxf(mxB, __shfl_xor(mxB, 32));
            float sA = 0.f, sB = 0.f;
            #pragma unroll
            for (int r = 0; r < 4; ++r) {
                f[0][r] = __expf(f[0][r] - mxA); sA += f[0][r];
                f[1][r] = __expf(f[1][r] - mxA); sA += f[1][r];
                f[2][r] = __expf(f[2][r] - mxB); sB += f[2][r];
                f[3][r] = __expf(f[3][r] - mxB); sB += f[3][r];
            }
            sA += __shfl_xor(sA, 16); sA += __shfl_xor(sA, 32);
            sB += __shfl_xor(sB, 16); sB += __shfl_xor(sB, 32);
            float iA = 1.f / sA, iB = 1.f / sB;
            #pragma unroll
            for (int m = 0; m < 4; ++m) {
                float sc = (m < 2) ? iA : iB;
                int rbase = wrow0 + wr * 64 + m * 16 + grp * 4;
                uint2 pk;
                pk.x = (uint)f2bf(f[m][0] * sc) | ((uint)f2bf(f[m][1] * sc) << 16);
                pk.y = (uint)f2bf(f[m][2] * sc) | ((uint)f2bf(f[m][3] * sc) << 16);
                *(uint2*)&qTb[(size_t)cg * 256 + rbase] = pk;
            }
        }
    } else {
        ushort* kvb = kvOut + (size_t)b * 512 * N_;
        #pragma unroll
        for (int n = 0; n < 4; ++n) {
            int cg = col0 + wc * 64 + n * 16 + (l & 15);
            #pragma unroll
            for (int m = 0; m < 4; ++m) {
                int rbase = wrow0 - 256 + wr * 64 + m * 16 + grp * 4;
                #pragma unroll
                for (int r = 0; r < 4; ++r)
                    kvb[(size_t)(rbase + r) * N_ + cg] = f2bf(acc[m][n][r]);
            }
        }
    }
}

// ---------------- K4: partial ctx = P @ V^T via MFMA, psum = P @ 1 --------
// kv layout: rows 0..255 = k (head h at h*32), rows 256..511 = v.
__global__ __launch_bounds__(256) void k_ctxpart(const ushort* __restrict__ kv,
                                                 float* __restrict__ ctxp,
                                                 float* __restrict__ sums_p) {
    __shared__ float red[4][32][33];
    __shared__ float redp[4][32];
    int bh = blockIdx.x, s = blockIdx.y;
    int b = bh >> 3, h = bh & 7;
    int t = threadIdx.x, l = t & 63, w = t >> 6;
    const ushort* kb = kv + (size_t)b * 512 * N_ + (size_t)(h * 32) * N_;
    const ushort* vb = kv + (size_t)b * 512 * N_ + (size_t)(256 + h * 32) * N_;
    const int n0base = s * 1024 + w * 256;
    const int row = l & 15, grp = l >> 4;
    f32x4 acc[2][2] = {};
    float psA = 0.f, psB = 0.f;

    for (int it = 0; it < 8; ++it) {
        int n0 = n0base + it * 32 + grp * 8;
        bf16x8 k0 = *(const bf16x8*)&kb[(size_t)row * N_ + n0];
        bf16x8 k1 = *(const bf16x8*)&kb[(size_t)(row + 16) * N_ + n0];
        bf16x8 v0 = *(const bf16x8*)&vb[(size_t)row * N_ + n0];
        bf16x8 v1 = *(const bf16x8*)&vb[(size_t)(row + 16) * N_ + n0];
        bf16x8 p0, p1;
        #pragma unroll
        for (int j = 0; j < 8; ++j) {
            ushort r0 = f2bf(__expf(bf2f((ushort)k0[j])));
            ushort r1 = f2bf(__expf(bf2f((ushort)k1[j])));
            p0[j] = (short)r0; p1[j] = (short)r1;
            psA += bf2f(r0); psB += bf2f(r1);
        }
        acc[0][0] = __builtin_amdgcn_mfma_f32_16x16x32_bf16(p0, v0, acc[0][0], 0, 0, 0);
        acc[0][1] = __builtin_amdgcn_mfma_f32_16x16x32_bf16(p0, v1, acc[0][1], 0, 0, 0);
        acc[1][0] = __builtin_amdgcn_mfma_f32_16x16x32_bf16(p1, v0, acc[1][0], 0, 0, 0);
        acc[1][1] = __builtin_amdgcn_mfma_f32_16x16x32_bf16(p1, v1, acc[1][1], 0, 0, 0);
    }

    psA += __shfl_xor(psA, 16); psA += __shfl_xor(psA, 32);
    psB += __shfl_xor(psB, 16); psB += __shfl_xor(psB, 32);
    #pragma unroll
    for (int mi = 0; mi < 2; ++mi)
        #pragma unroll
        for (int ni = 0; ni < 2; ++ni)
            #pragma unroll
            for (int r = 0; r < 4; ++r)
                red[w][mi * 16 + grp * 4 + r][ni * 16 + row] = acc[mi][ni][r];
    if (l < 16) { redp[w][l] = psA; redp[w][16 + l] = psB; }
    __syncthreads();

    size_t base = (size_t)(s * 128 + bh) * 32;
    #pragma unroll
    for (int i = t; i < 1024; i += 256) {
        int d = i >> 5, e = i & 31;
        ctxp[(base + d) * 32 + e] =
            red[0][d][e] + red[1][d][e] + red[2][d][e] + red[3][d][e];
    }
    if (t < 32)
        sums_p[base + t] = redp[0][t] + redp[1][t] + redp[2][t] + redp[3][t];
}

// ---------------- K5: M[b][o][h*32+d] = SCALE/stot[d] * sum_e w_out.ctx ----
__global__ __launch_bounds__(256) void k_fold(const float* __restrict__ w_out,
                                              const float* __restrict__ ctxp,
                                              const float* __restrict__ sums_p,
                                              ushort* __restrict__ M) {
    __shared__ float cn[32][33];     // [e][d]
    __shared__ float sinv[32];
    int bh = blockIdx.x;
    int b = bh >> 3, h = bh & 7;
    int t = threadIdx.x;
    if (t < 32) {
        float st = 0.f;
        #pragma unroll
        for (int s = 0; s < 4; ++s) st += sums_p[(size_t)(s * 128 + bh) * 32 + t];
        sinv[t] = SCALE_ / st;
    }
    #pragma unroll
    for (int i = t; i < 1024; i += 256) {
        int d = i >> 5, e = i & 31;
        float cv = 0.f;
        #pragma unroll
        for (int s = 0; s < 4; ++s)
            cv += ctxp[((size_t)(s * 128 + bh) * 32 + d) * 32 + e];
        cn[e][d] = cv;
    }
    __syncthreads();
    float wreg[32];
    const float* wr = w_out + (size_t)t * 256 + h * 32;
    #pragma unroll
    for (int e = 0; e < 32; e += 4) {
        float4 wv = *(const float4*)&wr[e];
        wreg[e] = wv.x; wreg[e + 1] = wv.y; wreg[e + 2] = wv.z; wreg[e + 3] = wv.w;
    }
    float acc[32] = {};
    #pragma unroll
    for (int e = 0; e < 32; ++e) {
        float we = wreg[e];
        #pragma unroll
        for (int d = 0; d < 32; ++d) acc[d] += we * cn[e][d];
    }
    ushort* Mrow = M + ((size_t)b * 256 + t) * 256 + h * 32;
    #pragma unroll
    for (int d = 0; d < 32; ++d) Mrow[d] = f2bf(acc[d] * sinv[d]);
}

// ---------------- K6: final = M @ q^T ; fused +b_out, RMSNorm*g2*16, +x ----
// tile 256x128, 8 waves (4x2), BK=32; B staged from qT[n][d] via uint4.
__global__ __launch_bounds__(512) void k_final(const ushort* __restrict__ M,
                                               const ushort* __restrict__ qT,
                                               const float* __restrict__ b_out,
                                               const float* __restrict__ g2,
                                               const float* __restrict__ x,
                                               float* __restrict__ out) {
    __shared__ ushort Asub[256][40];
    __shared__ ushort Bsub[128][40];
    __shared__ float ss2[4][128];
    int b = blockIdx.y;
    int col0 = blockIdx.x * 128;
    int t = threadIdx.x, l = t & 63, w = t >> 6;
    int wr = w >> 1, wc = w & 1;
    const ushort* Mb = M + (size_t)b * 256 * 256;
    const ushort* qTb = qT + (size_t)b * N_ * 256;
    f32x4 acc[4][4] = {};

    for (int k0 = 0; k0 < 256; k0 += 32) {
        {
            int r = t >> 1, ko = (t & 1) * 16;
            const uint4* src = (const uint4*)(Mb + (size_t)r * 256 + k0 + ko);
            *(uint4*)&Asub[r][ko]     = src[0];
            *(uint4*)&Asub[r][ko + 8] = src[1];
        }
        {
            int nl = t & 127, ko = (t >> 7) * 8;
            *(uint4*)&Bsub[nl][ko] =
                *(const uint4*)(qTb + (size_t)(col0 + nl) * 256 + k0 + ko);
        }
        __syncthreads();
        bf16x8 af[4], bfv[4];
        #pragma unroll
        for (int m = 0; m < 4; ++m)
            af[m] = *(const bf16x8*)&Asub[wr * 64 + m * 16 + (l & 15)][(l >> 4) * 8];
        #pragma unroll
        for (int n = 0; n < 4; ++n)
            bfv[n] = *(const bf16x8*)&Bsub[wc * 64 + n * 16 + (l & 15)][(l >> 4) * 8];
        #pragma unroll
        for (int m = 0; m < 4; ++m)
            #pragma unroll
            for (int n = 0; n < 4; ++n)
                acc[m][n] = __builtin_amdgcn_mfma_f32_16x16x32_bf16(af[m], bfv[n], acc[m][n], 0, 0, 0);
        __syncthreads();
    }

    #pragma unroll
    for (int n = 0; n < 4; ++n) {
        float local = 0.f;
        #pragma unroll
        for (int m = 0; m < 4; ++m) {
            int obase = wr * 64 + m * 16 + (l >> 4) * 4;
            #pragma unroll
            for (int r = 0; r < 4; ++r) {
                float f = acc[m][n][r] + b_out[obase + r];
                acc[m][n][r] = f;
                local += f * f;
            }
        }
        local += __shfl_xor(local, 16);
        local += __shfl_xor(local, 32);
        if ((l >> 4) == 0) ss2[wr][wc * 64 + n * 16 + (l & 15)] = local;
    }
    __syncthreads();
    const float* xb = x + (size_t)b * C_ * N_;
    float* ob = out + (size_t)b * C_ * N_;
    #pragma unroll
    for (int n = 0; n < 4; ++n) {
        int cl = wc * 64 + n * 16 + (l & 15);
        int cg = col0 + cl;
        float tot = ss2[0][cl] + ss2[1][cl] + ss2[2][cl] + ss2[3][cl];
        float rs = 16.f / fmaxf(sqrtf(tot), EPS_);
        #pragma unroll
        for (int m = 0; m < 4; ++m) {
            int obase = wr * 64 + m * 16 + (l >> 4) * 4;
            #pragma unroll
            for (int r = 0; r < 4; ++r) {
                int o = obase + r;
                ob[(size_t)o * N_ + cg] = acc[m][n][r] * rs * g2[o] + xb[(size_t)o * N_ + cg];
            }
        }
    }
}

extern "C" void kernel_launch(void* const* d_in, const int* in_sizes, int n_in,
                              void* d_out, int out_size, void* d_ws, size_t ws_size,
                              hipStream_t stream) {
    const float* x     = (const float*)d_in[0];
    const float* g1    = (const float*)d_in[1];
    const float* w_qkv = (const float*)d_in[2];
    const float* w_out = (const float*)d_in[3];
    const float* b_out = (const float*)d_in[4];
    const float* g2    = (const float*)d_in[5];
    float* out = (float*)d_out;
    char* ws = (char*)d_ws;

    ushort* Wp     = (ushort*)(ws + 0);          //    393216 B
    float*  ctxp   = (float*)(ws + 393216);      //   2097152 B
    float*  sums_p = (float*)(ws + 2490368);     //     65536 B
    ushort* Mm     = (ushort*)(ws + 2555904);    //   2097152 B
    ushort* xnbT   = (ushort*)(ws + 4653056);    //  33554432 B
    ushort* kv     = (ushort*)(ws + 38207488);   //  67108864 B (total 105.3 MB)
    ushort* qT     = kv;                         //  aliases kv (dead after ctxpart)

    k_prep<<<768, 256, 0, stream>>>(w_qkv, g1, Wp);
    k_xconv<<<dim3(64, 16), 256, 0, stream>>>(x, xnbT);
    k_gemm<<<dim3(32, 4, 16), 256, 0, stream>>>(Wp, xnbT, kv, nullptr, 0);
    k_ctxpart<<<dim3(128, 4), 256, 0, stream>>>(kv, ctxp, sums_p);
    k_fold<<<128, 256, 0, stream>>>(w_out, ctxp, sums_p, Mm);
    k_gemm<<<dim3(32, 2, 16), 256, 0, stream>>>(Wp, xnbT, nullptr, qT, 1);
    k_final<<<dim3(32, 16), 512, 0, stream>>>(Mm, qT, b_out, g2, x, out);
}

// Round 5
// 160.042 us; speedup vs baseline: 1.0083x; 1.0083x over previous
//
#include <hip/hip_runtime.h>
#include <math.h>

// LinearAttention: B=16, C=256, H=W=64 (N=4096), 8 heads x 32 dim.
// R1: k_fold -> block-per-(b,h) LDS kernel (was 114us latency-bound).
// R2: k_ctxpart -> MFMA fragments straight from global; q-softmax fused
//     into the qkv GEMM epilogue.
// R3: k_xconv pre-pass writes xnbT[n][c] = bf16(x*rinv) transposed (rinv
//     folded into x); GEMM staging becomes pure uint4 loads (was 16 scalar
//     fp32 loads + 16 f2bf per thread per K-step -> VALUBusy 54%).
//     q written transposed qT[n][d] so k_final B-staging is uint4 too.
//     qT aliases the kv buffer (kv dead after ctxpart) to stay <=105.6MB ws.

#define B_ 16
#define C_ 256
#define N_ 4096
#define SCALE_ 0.17677669529663687f
#define EPS_ 1e-12f

typedef __attribute__((ext_vector_type(8))) short bf16x8;
typedef __attribute__((ext_vector_type(4))) float f32x4;

__device__ __forceinline__ ushort f2bf(float f) {
    union { float f; uint u; } x; x.f = f;
    uint r = (x.u + 0x7FFFu + ((x.u >> 16) & 1u)) >> 16;
    return (ushort)r;
}
__device__ __forceinline__ float bf2f(ushort s) {
    union { uint u; float f; } x; x.u = ((uint)s) << 16;
    return x.f;
}

// ---------------- K1: W' = w_qkv * g1 -> bf16 ----------------
__global__ __launch_bounds__(256) void k_prep(const float* __restrict__ w_qkv,
                                              const float* __restrict__ g1,
                                              ushort* __restrict__ Wp) {
    int o = blockIdx.x, c = threadIdx.x;
    Wp[(size_t)o * 256 + c] = f2bf(w_qkv[(size_t)o * 256 + c] * g1[c]);
}

// ---------------- K2: xnbT[b][n][c] = bf16(x[b][c][n] * rinv[b][n]) -------
// block per (64-col n-tile, b); LDS transpose; rinv computed in-block.
__global__ __launch_bounds__(256) void k_xconv(const float* __restrict__ x,
                                               ushort* __restrict__ xnbT) {
    __shared__ float ssp[4][64];
    __shared__ float rinv_s[64];
    __shared__ ushort T[64][268];   // row stride 536B: 8B-aligned, 4-way-ish banks
    int b = blockIdx.y, n0 = blockIdx.x * 64;
    const float* xb = x + (size_t)b * C_ * N_ + n0;
    int t = threadIdx.x;
    int nl = t & 63, cg = t >> 6;    // cg: 0..3, 64 channels each
    float ss = 0.f;
    #pragma unroll 8
    for (int i = 0; i < 64; ++i) {
        float v = xb[(size_t)(cg * 64 + i) * N_ + nl];
        ss += v * v;
    }
    ssp[cg][nl] = ss;
    __syncthreads();
    if (t < 64)
        rinv_s[t] = 16.f / fmaxf(sqrtf(ssp[0][t] + ssp[1][t] + ssp[2][t] + ssp[3][t]), EPS_);
    __syncthreads();
    float rv = rinv_s[nl];
    #pragma unroll 8
    for (int i = 0; i < 64; ++i) {
        int c = cg * 64 + i;
        T[nl][c] = f2bf(xb[(size_t)c * N_ + nl] * rv);   // L2-hot re-read
    }
    __syncthreads();
    int j = t >> 2, ch = t & 3;
    ushort* orow = xnbT + ((size_t)b * N_ + n0 + j) * 256 + ch * 64;
    #pragma unroll
    for (int i = 0; i < 8; ++i)
        *(uint2*)&orow[i * 8] = *(const uint2*)&T[j][ch * 64 + i * 8],
        *(uint2*)&orow[i * 8 + 4] = *(const uint2*)&T[j][ch * 64 + i * 8 + 4];
}

// ---------------- K3: GEMM  C = Wp[rows] @ xn  (both bf16 row-major) ------
// tile 128x128, BK=32, 4 waves each 64x64 via 16x16x32 MFMA.
// qmode=0: rows 256..767 -> kv[d][n] layout.
// qmode=1: rows 0..255 -> per-head softmax over d -> qT[n][d] layout.
__global__ __launch_bounds__(256) void k_gemm(const ushort* __restrict__ Wp,
                                              const ushort* __restrict__ xnbT,
                                              ushort* __restrict__ kvOut,
                                              ushort* __restrict__ qTOut,
                                              int qmode) {
    __shared__ ushort Asub[128][40];
    __shared__ ushort Bsub[128][40];
    const int b = blockIdx.z;
    const int wrow0 = (qmode ? 0 : 256) + blockIdx.y * 128;
    const int col0 = blockIdx.x * 128;
    const int t = threadIdx.x;
    const int l = t & 63, w = t >> 6;
    const int wr = w >> 1, wc = w & 1, grp = l >> 4;
    const ushort* xb = xnbT + (size_t)b * N_ * 256;
    f32x4 acc[4][4] = {};

    for (int k0 = 0; k0 < 256; k0 += 32) {
        int r = t >> 1, ko = (t & 1) * 16;
        const uint4* sa = (const uint4*)(Wp + (size_t)(wrow0 + r) * 256 + k0 + ko);
        *(uint4*)&Asub[r][ko]     = sa[0];
        *(uint4*)&Asub[r][ko + 8] = sa[1];
        const uint4* sb = (const uint4*)(xb + (size_t)(col0 + r) * 256 + k0 + ko);
        *(uint4*)&Bsub[r][ko]     = sb[0];
        *(uint4*)&Bsub[r][ko + 8] = sb[1];
        __syncthreads();
        bf16x8 af[4], bfv[4];
        #pragma unroll
        for (int m = 0; m < 4; ++m)
            af[m] = *(const bf16x8*)&Asub[wr * 64 + m * 16 + (l & 15)][grp * 8];
        #pragma unroll
        for (int n = 0; n < 4; ++n)
            bfv[n] = *(const bf16x8*)&Bsub[wc * 64 + n * 16 + (l & 15)][grp * 8];
        #pragma unroll
        for (int m = 0; m < 4; ++m)
            #pragma unroll
            for (int n = 0; n < 4; ++n)
                acc[m][n] = __builtin_amdgcn_mfma_f32_16x16x32_bf16(af[m], bfv[n], acc[m][n], 0, 0, 0);
        __syncthreads();
    }

    if (qmode) {
        ushort* qTb = qTOut + (size_t)b * N_ * 256;
        #pragma unroll
        for (int n = 0; n < 4; ++n) {
            int cg = col0 + wc * 64 + n * 16 + (l & 15);
            float f[4][4];
            #pragma unroll
            for (int m = 0; m < 4; ++m)
                #pragma unroll
                for (int r = 0; r < 4; ++r) f[m][r] = acc[m][n][r];
            // m=0,1 -> one head (32 d), m=2,3 -> next head
            float mxA = -1e30f, mxB = -1e30f;
            #pragma unroll
            for (int r = 0; r < 4; ++r) {
                mxA = fmaxf(mxA, fmaxf(f[0][r], f[1][r]));
                mxB = fmaxf(mxB, fmaxf(f[2][r], f[3][r]));
            }
            mxA = fmaxf(mxA, __shfl_xor(mxA, 16));
            mxA = fmaxf(mxA, __shfl_xor(mxA, 32));
            mxB = fmaxf(mxB, __shfl_xor(mxB, 16));
            mxB = fmaxf(mxB, __shfl_xor(mxB, 32));
            float sA = 0.f, sB = 0.f;
            #pragma unroll
            for (int r = 0; r < 4; ++r) {
                f[0][r] = __expf(f[0][r] - mxA); sA += f[0][r];
                f[1][r] = __expf(f[1][r] - mxA); sA += f[1][r];
                f[2][r] = __expf(f[2][r] - mxB); sB += f[2][r];
                f[3][r] = __expf(f[3][r] - mxB); sB += f[3][r];
            }
            sA += __shfl_xor(sA, 16); sA += __shfl_xor(sA, 32);
            sB += __shfl_xor(sB, 16); sB += __shfl_xor(sB, 32);
            float iA = 1.f / sA, iB = 1.f / sB;
            #pragma unroll
            for (int m = 0; m < 4; ++m) {
                float sc = (m < 2) ? iA : iB;
                int rbase = wrow0 + wr * 64 + m * 16 + grp * 4;
                uint2 pk;
                pk.x = (uint)f2bf(f[m][0] * sc) | ((uint)f2bf(f[m][1] * sc) << 16);
                pk.y = (uint)f2bf(f[m][2] * sc) | ((uint)f2bf(f[m][3] * sc) << 16);
                *(uint2*)&qTb[(size_t)cg * 256 + rbase] = pk;
            }
        }
    } else {
        ushort* kvb = kvOut + (size_t)b * 512 * N_;
        #pragma unroll
        for (int n = 0; n < 4; ++n) {
            int cg = col0 + wc * 64 + n * 16 + (l & 15);
            #pragma unroll
            for (int m = 0; m < 4; ++m) {
                int rbase = wrow0 - 256 + wr * 64 + m * 16 + grp * 4;
                #pragma unroll
                for (int r = 0; r < 4; ++r)
                    kvb[(size_t)(rbase + r) * N_ + cg] = f2bf(acc[m][n][r]);
            }
        }
    }
}

// ---------------- K4: partial ctx = P @ V^T via MFMA, psum = P @ 1 --------
// kv layout: rows 0..255 = k (head h at h*32), rows 256..511 = v.
__global__ __launch_bounds__(256) void k_ctxpart(const ushort* __restrict__ kv,
                                                 float* __restrict__ ctxp,
                                                 float* __restrict__ sums_p) {
    __shared__ float red[4][32][33];
    __shared__ float redp[4][32];
    int bh = blockIdx.x, s = blockIdx.y;
    int b = bh >> 3, h = bh & 7;
    int t = threadIdx.x, l = t & 63, w = t >> 6;
    const ushort* kb = kv + (size_t)b * 512 * N_ + (size_t)(h * 32) * N_;
    const ushort* vb = kv + (size_t)b * 512 * N_ + (size_t)(256 + h * 32) * N_;
    const int n0base = s * 1024 + w * 256;
    const int row = l & 15, grp = l >> 4;
    f32x4 acc[2][2] = {};
    float psA = 0.f, psB = 0.f;

    for (int it = 0; it < 8; ++it) {
        int n0 = n0base + it * 32 + grp * 8;
        bf16x8 k0 = *(const bf16x8*)&kb[(size_t)row * N_ + n0];
        bf16x8 k1 = *(const bf16x8*)&kb[(size_t)(row + 16) * N_ + n0];
        bf16x8 v0 = *(const bf16x8*)&vb[(size_t)row * N_ + n0];
        bf16x8 v1 = *(const bf16x8*)&vb[(size_t)(row + 16) * N_ + n0];
        bf16x8 p0, p1;
        #pragma unroll
        for (int j = 0; j < 8; ++j) {
            ushort r0 = f2bf(__expf(bf2f((ushort)k0[j])));
            ushort r1 = f2bf(__expf(bf2f((ushort)k1[j])));
            p0[j] = (short)r0; p1[j] = (short)r1;
            psA += bf2f(r0); psB += bf2f(r1);
        }
        acc[0][0] = __builtin_amdgcn_mfma_f32_16x16x32_bf16(p0, v0, acc[0][0], 0, 0, 0);
        acc[0][1] = __builtin_amdgcn_mfma_f32_16x16x32_bf16(p0, v1, acc[0][1], 0, 0, 0);
        acc[1][0] = __builtin_amdgcn_mfma_f32_16x16x32_bf16(p1, v0, acc[1][0], 0, 0, 0);
        acc[1][1] = __builtin_amdgcn_mfma_f32_16x16x32_bf16(p1, v1, acc[1][1], 0, 0, 0);
    }

    psA += __shfl_xor(psA, 16); psA += __shfl_xor(psA, 32);
    psB += __shfl_xor(psB, 16); psB += __shfl_xor(psB, 32);
    #pragma unroll
    for (int mi = 0; mi < 2; ++mi)
        #pragma unroll
        for (int ni = 0; ni < 2; ++ni)
            #pragma unroll
            for (int r = 0; r < 4; ++r)
                red[w][mi * 16 + grp * 4 + r][ni * 16 + row] = acc[mi][ni][r];
    if (l < 16) { redp[w][l] = psA; redp[w][16 + l] = psB; }
    __syncthreads();

    size_t base = (size_t)(s * 128 + bh) * 32;
    #pragma unroll
    for (int i = t; i < 1024; i += 256) {
        int d = i >> 5, e = i & 31;
        ctxp[(base + d) * 32 + e] =
            red[0][d][e] + red[1][d][e] + red[2][d][e] + red[3][d][e];
    }
    if (t < 32)
        sums_p[base + t] = redp[0][t] + redp[1][t] + redp[2][t] + redp[3][t];
}

// ---------------- K5: M[b][o][h*32+d] = SCALE/stot[d] * sum_e w_out.ctx ----
__global__ __launch_bounds__(256) void k_fold(const float* __restrict__ w_out,
                                              const float* __restrict__ ctxp,
                                              const float* __restrict__ sums_p,
                                              ushort* __restrict__ M) {
    __shared__ float cn[32][33];     // [e][d]
    __shared__ float sinv[32];
    int bh = blockIdx.x;
    int b = bh >> 3, h = bh & 7;
    int t = threadIdx.x;
    if (t < 32) {
        float st = 0.f;
        #pragma unroll
        for (int s = 0; s < 4; ++s) st += sums_p[(size_t)(s * 128 + bh) * 32 + t];
        sinv[t] = SCALE_ / st;
    }
    #pragma unroll
    for (int i = t; i < 1024; i += 256) {
        int d = i >> 5, e = i & 31;
        float cv = 0.f;
        #pragma unroll
        for (int s = 0; s < 4; ++s)
            cv += ctxp[((size_t)(s * 128 + bh) * 32 + d) * 32 + e];
        cn[e][d] = cv;
    }
    __syncthreads();
    float wreg[32];
    const float* wr = w_out + (size_t)t * 256 + h * 32;
    #pragma unroll
    for (int e = 0; e < 32; e += 4) {
        float4 wv = *(const float4*)&wr[e];
        wreg[e] = wv.x; wreg[e + 1] = wv.y; wreg[e + 2] = wv.z; wreg[e + 3] = wv.w;
    }
    float acc[32] = {};
    #pragma unroll
    for (int e = 0; e < 32; ++e) {
        float we = wreg[e];
        #pragma unroll
        for (int d = 0; d < 32; ++d) acc[d] += we * cn[e][d];
    }
    ushort* Mrow = M + ((size_t)b * 256 + t) * 256 + h * 32;
    #pragma unroll
    for (int d = 0; d < 32; ++d) Mrow[d] = f2bf(acc[d] * sinv[d]);
}

// ---------------- K6: final = M @ q^T ; fused +b_out, RMSNorm*g2*16, +x ----
// tile 256x128, 8 waves (4x2), BK=32; B staged from qT[n][d] via uint4.
__global__ __launch_bounds__(512) void k_final(const ushort* __restrict__ M,
                                               const ushort* __restrict__ qT,
                                               const float* __restrict__ b_out,
                                               const float* __restrict__ g2,
                                               const float* __restrict__ x,
                                               float* __restrict__ out) {
    __shared__ ushort Asub[256][40];
    __shared__ ushort Bsub[128][40];
    __shared__ float ss2[4][128];
    int b = blockIdx.y;
    int col0 = blockIdx.x * 128;
    int t = threadIdx.x, l = t & 63, w = t >> 6;
    int wr = w >> 1, wc = w & 1;
    const ushort* Mb = M + (size_t)b * 256 * 256;
    const ushort* qTb = qT + (size_t)b * N_ * 256;
    f32x4 acc[4][4] = {};

    for (int k0 = 0; k0 < 256; k0 += 32) {
        {
            int r = t >> 1, ko = (t & 1) * 16;
            const uint4* src = (const uint4*)(Mb + (size_t)r * 256 + k0 + ko);
            *(uint4*)&Asub[r][ko]     = src[0];
            *(uint4*)&Asub[r][ko + 8] = src[1];
        }
        {
            int nl = t & 127, ko = (t >> 7) * 8;
            *(uint4*)&Bsub[nl][ko] =
                *(const uint4*)(qTb + (size_t)(col0 + nl) * 256 + k0 + ko);
        }
        __syncthreads();
        bf16x8 af[4], bfv[4];
        #pragma unroll
        for (int m = 0; m < 4; ++m)
            af[m] = *(const bf16x8*)&Asub[wr * 64 + m * 16 + (l & 15)][(l >> 4) * 8];
        #pragma unroll
        for (int n = 0; n < 4; ++n)
            bfv[n] = *(const bf16x8*)&Bsub[wc * 64 + n * 16 + (l & 15)][(l >> 4) * 8];
        #pragma unroll
        for (int m = 0; m < 4; ++m)
            #pragma unroll
            for (int n = 0; n < 4; ++n)
                acc[m][n] = __builtin_amdgcn_mfma_f32_16x16x32_bf16(af[m], bfv[n], acc[m][n], 0, 0, 0);
        __syncthreads();
    }

    #pragma unroll
    for (int n = 0; n < 4; ++n) {
        float local = 0.f;
        #pragma unroll
        for (int m = 0; m < 4; ++m) {
            int obase = wr * 64 + m * 16 + (l >> 4) * 4;
            #pragma unroll
            for (int r = 0; r < 4; ++r) {
                float f = acc[m][n][r] + b_out[obase + r];
                acc[m][n][r] = f;
                local += f * f;
            }
        }
        local += __shfl_xor(local, 16);
        local += __shfl_xor(local, 32);
        if ((l >> 4) == 0) ss2[wr][wc * 64 + n * 16 + (l & 15)] = local;
    }
    __syncthreads();
    const float* xb = x + (size_t)b * C_ * N_;
    float* ob = out + (size_t)b * C_ * N_;
    #pragma unroll
    for (int n = 0; n < 4; ++n) {
        int cl = wc * 64 + n * 16 + (l & 15);
        int cg = col0 + cl;
        float tot = ss2[0][cl] + ss2[1][cl] + ss2[2][cl] + ss2[3][cl];
        float rs = 16.f / fmaxf(sqrtf(tot), EPS_);
        #pragma unroll
        for (int m = 0; m < 4; ++m) {
            int obase = wr * 64 + m * 16 + (l >> 4) * 4;
            #pragma unroll
            for (int r = 0; r < 4; ++r) {
                int o = obase + r;
                ob[(size_t)o * N_ + cg] = acc[m][n][r] * rs * g2[o] + xb[(size_t)o * N_ + cg];
            }
        }
    }
}

extern "C" void kernel_launch(void* const* d_in, const int* in_sizes, int n_in,
                              void* d_out, int out_size, void* d_ws, size_t ws_size,
                              hipStream_t stream) {
    const float* x     = (const float*)d_in[0];
    const float* g1    = (const float*)d_in[1];
    const float* w_qkv = (const float*)d_in[2];
    const float* w_out = (const float*)d_in[3];
    const float* b_out = (const float*)d_in[4];
    const float* g2    = (const float*)d_in[5];
    float* out = (float*)d_out;
    char* ws = (char*)d_ws;

    ushort* Wp     = (ushort*)(ws + 0);          //    393216 B
    float*  ctxp   = (float*)(ws + 393216);      //   2097152 B
    float*  sums_p = (float*)(ws + 2490368);     //     65536 B
    ushort* Mm     = (ushort*)(ws + 2555904);    //   2097152 B
    ushort* xnbT   = (ushort*)(ws + 4653056);    //  33554432 B
    ushort* kv     = (ushort*)(ws + 38207488);   //  67108864 B (total 105.3 MB)
    ushort* qT     = kv;                         //  aliases kv (dead after ctxpart)

    k_prep<<<768, 256, 0, stream>>>(w_qkv, g1, Wp);
    k_xconv<<<dim3(64, 16), 256, 0, stream>>>(x, xnbT);
    k_gemm<<<dim3(32, 4, 16), 256, 0, stream>>>(Wp, xnbT, kv, nullptr, 0);
    k_ctxpart<<<dim3(128, 4), 256, 0, stream>>>(kv, ctxp, sums_p);
    k_fold<<<128, 256, 0, stream>>>(w_out, ctxp, sums_p, Mm);
    k_gemm<<<dim3(32, 2, 16), 256, 0, stream>>>(Wp, xnbT, nullptr, qT, 1);
    k_final<<<dim3(32, 16), 512, 0, stream>>>(Mm, qT, b_out, g2, x, out);
}

// Round 6
// 152.319 us; speedup vs baseline: 1.0594x; 1.0507x over previous
//
#include <hip/hip_runtime.h>
#include <math.h>

// LinearAttention: B=16, C=256, H=W=64 (N=4096), 8 heads x 32 dim.
// R1: k_fold -> block-per-(b,h) LDS kernel (was 114us latency-bound).
// R2: k_ctxpart -> MFMA fragments straight from global; q-softmax fused
//     into the qkv GEMM epilogue.
// R3: xnbT pre-transpose (rinv folded); all GEMM staging pure uint4.
// R6: fuse q-GEMM + softmax + M@q + (b_out, RMSNorm, +x) epilogue into
//     k_qfinal (deletes 64MB qT round-trip + one dispatch; k_final was
//     grid-limited at 512 blocks / 3.2 TB/s). q handoff via XOR-swizzled
//     LDS ( byte ^= (col&7)<<4 , both sides). k_gemm is now kv-only.

#define B_ 16
#define C_ 256
#define N_ 4096
#define SCALE_ 0.17677669529663687f
#define EPS_ 1e-12f

typedef __attribute__((ext_vector_type(8))) short bf16x8;
typedef __attribute__((ext_vector_type(4))) float f32x4;

__device__ __forceinline__ ushort f2bf(float f) {
    union { float f; uint u; } x; x.f = f;
    uint r = (x.u + 0x7FFFu + ((x.u >> 16) & 1u)) >> 16;
    return (ushort)r;
}
__device__ __forceinline__ float bf2f(ushort s) {
    union { uint u; float f; } x; x.u = ((uint)s) << 16;
    return x.f;
}

// ---------------- K1: W' = w_qkv * g1 -> bf16 ----------------
__global__ __launch_bounds__(256) void k_prep(const float* __restrict__ w_qkv,
                                              const float* __restrict__ g1,
                                              ushort* __restrict__ Wp) {
    int o = blockIdx.x, c = threadIdx.x;
    Wp[(size_t)o * 256 + c] = f2bf(w_qkv[(size_t)o * 256 + c] * g1[c]);
}

// ---------------- K2: xnbT[b][n][c] = bf16(x[b][c][n] * rinv[b][n]) -------
__global__ __launch_bounds__(256) void k_xconv(const float* __restrict__ x,
                                               ushort* __restrict__ xnbT) {
    __shared__ float ssp[4][64];
    __shared__ float rinv_s[64];
    __shared__ ushort T[64][268];
    int b = blockIdx.y, n0 = blockIdx.x * 64;
    const float* xb = x + (size_t)b * C_ * N_ + n0;
    int t = threadIdx.x;
    int nl = t & 63, cg = t >> 6;
    float ss = 0.f;
    #pragma unroll 8
    for (int i = 0; i < 64; ++i) {
        float v = xb[(size_t)(cg * 64 + i) * N_ + nl];
        ss += v * v;
    }
    ssp[cg][nl] = ss;
    __syncthreads();
    if (t < 64)
        rinv_s[t] = 16.f / fmaxf(sqrtf(ssp[0][t] + ssp[1][t] + ssp[2][t] + ssp[3][t]), EPS_);
    __syncthreads();
    float rv = rinv_s[nl];
    #pragma unroll 8
    for (int i = 0; i < 64; ++i) {
        int c = cg * 64 + i;
        T[nl][c] = f2bf(xb[(size_t)c * N_ + nl] * rv);   // L2-hot re-read
    }
    __syncthreads();
    int j = t >> 2, ch = t & 3;
    ushort* orow = xnbT + ((size_t)b * N_ + n0 + j) * 256 + ch * 64;
    #pragma unroll
    for (int i = 0; i < 8; ++i)
        *(uint2*)&orow[i * 8] = *(const uint2*)&T[j][ch * 64 + i * 8],
        *(uint2*)&orow[i * 8 + 4] = *(const uint2*)&T[j][ch * 64 + i * 8 + 4];
}

// ---------------- K3: kv GEMM  kv = Wp[256..767] @ xn ----------------
// tile 128x128, BK=32, 4 waves each 64x64 via 16x16x32 MFMA.
__global__ __launch_bounds__(256) void k_gemm(const ushort* __restrict__ Wp,
                                              const ushort* __restrict__ xnbT,
                                              ushort* __restrict__ kvOut) {
    __shared__ ushort Asub[128][40];
    __shared__ ushort Bsub[128][40];
    const int b = blockIdx.z;
    const int wrow0 = 256 + blockIdx.y * 128;
    const int col0 = blockIdx.x * 128;
    const int t = threadIdx.x;
    const int l = t & 63, w = t >> 6;
    const int wr = w >> 1, wc = w & 1, grp = l >> 4;
    const ushort* xb = xnbT + (size_t)b * N_ * 256;
    f32x4 acc[4][4] = {};

    for (int k0 = 0; k0 < 256; k0 += 32) {
        int r = t >> 1, ko = (t & 1) * 16;
        const uint4* sa = (const uint4*)(Wp + (size_t)(wrow0 + r) * 256 + k0 + ko);
        *(uint4*)&Asub[r][ko]     = sa[0];
        *(uint4*)&Asub[r][ko + 8] = sa[1];
        const uint4* sb = (const uint4*)(xb + (size_t)(col0 + r) * 256 + k0 + ko);
        *(uint4*)&Bsub[r][ko]     = sb[0];
        *(uint4*)&Bsub[r][ko + 8] = sb[1];
        __syncthreads();
        bf16x8 af[4], bfv[4];
        #pragma unroll
        for (int m = 0; m < 4; ++m)
            af[m] = *(const bf16x8*)&Asub[wr * 64 + m * 16 + (l & 15)][grp * 8];
        #pragma unroll
        for (int n = 0; n < 4; ++n)
            bfv[n] = *(const bf16x8*)&Bsub[wc * 64 + n * 16 + (l & 15)][grp * 8];
        #pragma unroll
        for (int m = 0; m < 4; ++m)
            #pragma unroll
            for (int n = 0; n < 4; ++n)
                acc[m][n] = __builtin_amdgcn_mfma_f32_16x16x32_bf16(af[m], bfv[n], acc[m][n], 0, 0, 0);
        __syncthreads();
    }

    ushort* kvb = kvOut + (size_t)b * 512 * N_;
    #pragma unroll
    for (int n = 0; n < 4; ++n) {
        int cg = col0 + wc * 64 + n * 16 + (l & 15);
        #pragma unroll
        for (int m = 0; m < 4; ++m) {
            int rbase = wrow0 - 256 + wr * 64 + m * 16 + grp * 4;
            #pragma unroll
            for (int r = 0; r < 4; ++r)
                kvb[(size_t)(rbase + r) * N_ + cg] = f2bf(acc[m][n][r]);
        }
    }
}

// ---------------- K4: partial ctx = P @ V^T via MFMA, psum = P @ 1 --------
__global__ __launch_bounds__(256) void k_ctxpart(const ushort* __restrict__ kv,
                                                 float* __restrict__ ctxp,
                                                 float* __restrict__ sums_p) {
    __shared__ float red[4][32][33];
    __shared__ float redp[4][32];
    int bh = blockIdx.x, s = blockIdx.y;
    int b = bh >> 3, h = bh & 7;
    int t = threadIdx.x, l = t & 63, w = t >> 6;
    const ushort* kb = kv + (size_t)b * 512 * N_ + (size_t)(h * 32) * N_;
    const ushort* vb = kv + (size_t)b * 512 * N_ + (size_t)(256 + h * 32) * N_;
    const int n0base = s * 1024 + w * 256;
    const int row = l & 15, grp = l >> 4;
    f32x4 acc[2][2] = {};
    float psA = 0.f, psB = 0.f;

    for (int it = 0; it < 8; ++it) {
        int n0 = n0base + it * 32 + grp * 8;
        bf16x8 k0 = *(const bf16x8*)&kb[(size_t)row * N_ + n0];
        bf16x8 k1 = *(const bf16x8*)&kb[(size_t)(row + 16) * N_ + n0];
        bf16x8 v0 = *(const bf16x8*)&vb[(size_t)row * N_ + n0];
        bf16x8 v1 = *(const bf16x8*)&vb[(size_t)(row + 16) * N_ + n0];
        bf16x8 p0, p1;
        #pragma unroll
        for (int j = 0; j < 8; ++j) {
            ushort r0 = f2bf(__expf(bf2f((ushort)k0[j])));
            ushort r1 = f2bf(__expf(bf2f((ushort)k1[j])));
            p0[j] = (short)r0; p1[j] = (short)r1;
            psA += bf2f(r0); psB += bf2f(r1);
        }
        acc[0][0] = __builtin_amdgcn_mfma_f32_16x16x32_bf16(p0, v0, acc[0][0], 0, 0, 0);
        acc[0][1] = __builtin_amdgcn_mfma_f32_16x16x32_bf16(p0, v1, acc[0][1], 0, 0, 0);
        acc[1][0] = __builtin_amdgcn_mfma_f32_16x16x32_bf16(p1, v0, acc[1][0], 0, 0, 0);
        acc[1][1] = __builtin_amdgcn_mfma_f32_16x16x32_bf16(p1, v1, acc[1][1], 0, 0, 0);
    }

    psA += __shfl_xor(psA, 16); psA += __shfl_xor(psA, 32);
    psB += __shfl_xor(psB, 16); psB += __shfl_xor(psB, 32);
    #pragma unroll
    for (int mi = 0; mi < 2; ++mi)
        #pragma unroll
        for (int ni = 0; ni < 2; ++ni)
            #pragma unroll
            for (int r = 0; r < 4; ++r)
                red[w][mi * 16 + grp * 4 + r][ni * 16 + row] = acc[mi][ni][r];
    if (l < 16) { redp[w][l] = psA; redp[w][16 + l] = psB; }
    __syncthreads();

    size_t base = (size_t)(s * 128 + bh) * 32;
    #pragma unroll
    for (int i = t; i < 1024; i += 256) {
        int d = i >> 5, e = i & 31;
        ctxp[(base + d) * 32 + e] =
            red[0][d][e] + red[1][d][e] + red[2][d][e] + red[3][d][e];
    }
    if (t < 32)
        sums_p[base + t] = redp[0][t] + redp[1][t] + redp[2][t] + redp[3][t];
}

// ---------------- K5: M[b][o][h*32+d] = SCALE/stot[d] * sum_e w_out.ctx ----
__global__ __launch_bounds__(256) void k_fold(const float* __restrict__ w_out,
                                              const float* __restrict__ ctxp,
                                              const float* __restrict__ sums_p,
                                              ushort* __restrict__ M) {
    __shared__ float cn[32][33];
    __shared__ float sinv[32];
    int bh = blockIdx.x;
    int b = bh >> 3, h = bh & 7;
    int t = threadIdx.x;
    if (t < 32) {
        float st = 0.f;
        #pragma unroll
        for (int s = 0; s < 4; ++s) st += sums_p[(size_t)(s * 128 + bh) * 32 + t];
        sinv[t] = SCALE_ / st;
    }
    #pragma unroll
    for (int i = t; i < 1024; i += 256) {
        int d = i >> 5, e = i & 31;
        float cv = 0.f;
        #pragma unroll
        for (int s = 0; s < 4; ++s)
            cv += ctxp[((size_t)(s * 128 + bh) * 32 + d) * 32 + e];
        cn[e][d] = cv;
    }
    __syncthreads();
    float wreg[32];
    const float* wr = w_out + (size_t)t * 256 + h * 32;
    #pragma unroll
    for (int e = 0; e < 32; e += 4) {
        float4 wv = *(const float4*)&wr[e];
        wreg[e] = wv.x; wreg[e + 1] = wv.y; wreg[e + 2] = wv.z; wreg[e + 3] = wv.w;
    }
    float acc[32] = {};
    #pragma unroll
    for (int e = 0; e < 32; ++e) {
        float we = wreg[e];
        #pragma unroll
        for (int d = 0; d < 32; ++d) acc[d] += we * cn[e][d];
    }
    ushort* Mrow = M + ((size_t)b * 256 + t) * 256 + h * 32;
    #pragma unroll
    for (int d = 0; d < 32; ++d) Mrow[d] = f2bf(acc[d] * sinv[d]);
}

// ---------------- K6: fused q-GEMM + softmax + M@q + epilogue ----------
// grid (64 coltiles, 16 b), 512 threads = 8 waves; each wave 32 out-rows.
// GEMM1: q = Wp[0..255] @ xn(64 cols); per-head softmax (head = wave id);
// q -> XOR-swizzled LDS; GEMM2: out = M @ q; +b_out, RMSNorm*g2*16, +x.
__global__ __launch_bounds__(512) void k_qfinal(const ushort* __restrict__ Wp,
                                                const ushort* __restrict__ xnbT,
                                                const ushort* __restrict__ M,
                                                const float* __restrict__ b_out,
                                                const float* __restrict__ g2,
                                                const float* __restrict__ x,
                                                float* __restrict__ out) {
    __shared__ ushort Asub[256][40];
    __shared__ ushort Bsub[64][40];
    __shared__ ushort qlds[64 * 256];   // [col][d], byte ^= (col&7)<<4
    __shared__ float ss2[8][64];
    const int b = blockIdx.y, col0 = blockIdx.x * 64;
    const int t = threadIdx.x, l = t & 63, w = t >> 6;   // w = head = row-group
    const int lr = l & 15, grp = l >> 4;
    const ushort* xb = xnbT + (size_t)b * N_ * 256;
    f32x4 acc[2][4] = {};

    // ---- GEMM1: q = Wq @ xn ----
    for (int k0 = 0; k0 < 256; k0 += 32) {
        { int r = t >> 1, ko = (t & 1) * 16;
          const uint4* sa = (const uint4*)(Wp + (size_t)r * 256 + k0 + ko);
          *(uint4*)&Asub[r][ko]     = sa[0];
          *(uint4*)&Asub[r][ko + 8] = sa[1]; }
        if (t < 128) {
          int r = t >> 1, ko = (t & 1) * 16;
          const uint4* sb = (const uint4*)(xb + (size_t)(col0 + r) * 256 + k0 + ko);
          *(uint4*)&Bsub[r][ko]     = sb[0];
          *(uint4*)&Bsub[r][ko + 8] = sb[1]; }
        __syncthreads();
        bf16x8 af[2], bfv[4];
        #pragma unroll
        for (int m = 0; m < 2; ++m)
            af[m] = *(const bf16x8*)&Asub[w * 32 + m * 16 + lr][grp * 8];
        #pragma unroll
        for (int n = 0; n < 4; ++n)
            bfv[n] = *(const bf16x8*)&Bsub[n * 16 + lr][grp * 8];
        #pragma unroll
        for (int m = 0; m < 2; ++m)
            #pragma unroll
            for (int n = 0; n < 4; ++n)
                acc[m][n] = __builtin_amdgcn_mfma_f32_16x16x32_bf16(af[m], bfv[n], acc[m][n], 0, 0, 0);
        __syncthreads();
    }

    // ---- per-head softmax over d (wave = head, 32 rows), write qlds ----
    #pragma unroll
    for (int n = 0; n < 4; ++n) {
        float f[2][4];
        #pragma unroll
        for (int m = 0; m < 2; ++m)
            #pragma unroll
            for (int r = 0; r < 4; ++r) f[m][r] = acc[m][n][r];
        float mx = -1e30f;
        #pragma unroll
        for (int r = 0; r < 4; ++r) mx = fmaxf(mx, fmaxf(f[0][r], f[1][r]));
        mx = fmaxf(mx, __shfl_xor(mx, 16));
        mx = fmaxf(mx, __shfl_xor(mx, 32));
        float s = 0.f;
        #pragma unroll
        for (int r = 0; r < 4; ++r) {
            f[0][r] = __expf(f[0][r] - mx); s += f[0][r];
            f[1][r] = __expf(f[1][r] - mx); s += f[1][r];
        }
        s += __shfl_xor(s, 16); s += __shfl_xor(s, 32);
        float inv = 1.f / s;
        int cl = n * 16 + lr;
        #pragma unroll
        for (int m = 0; m < 2; ++m) {
            int d = w * 32 + m * 16 + grp * 4;
            uint2 pk;
            pk.x = (uint)f2bf(f[m][0] * inv) | ((uint)f2bf(f[m][1] * inv) << 16);
            pk.y = (uint)f2bf(f[m][2] * inv) | ((uint)f2bf(f[m][3] * inv) << 16);
            uint off = (uint)(cl * 512 + d * 2) ^ (uint)((cl & 7) << 4);
            *(uint2*)((char*)qlds + off) = pk;
        }
    }

    // ---- GEMM2: out = M @ q ----
    f32x4 acc2[2][4] = {};
    const ushort* Mb = M + (size_t)b * 256 * 256;
    for (int k0 = 0; k0 < 256; k0 += 32) {
        { int r = t >> 1, ko = (t & 1) * 16;
          const uint4* sa = (const uint4*)(Mb + (size_t)r * 256 + k0 + ko);
          *(uint4*)&Asub[r][ko]     = sa[0];
          *(uint4*)&Asub[r][ko + 8] = sa[1]; }
        __syncthreads();   // first iter also fences qlds writes
        bf16x8 af[2], bq[4];
        #pragma unroll
        for (int m = 0; m < 2; ++m)
            af[m] = *(const bf16x8*)&Asub[w * 32 + m * 16 + lr][grp * 8];
        #pragma unroll
        for (int n = 0; n < 4; ++n) {
            int row = n * 16 + lr;
            uint off = (uint)(row * 512 + (k0 + grp * 8) * 2) ^ (uint)((row & 7) << 4);
            bq[n] = *(const bf16x8*)((const char*)qlds + off);
        }
        #pragma unroll
        for (int m = 0; m < 2; ++m)
            #pragma unroll
            for (int n = 0; n < 4; ++n)
                acc2[m][n] = __builtin_amdgcn_mfma_f32_16x16x32_bf16(af[m], bq[n], acc2[m][n], 0, 0, 0);
        __syncthreads();
    }

    // ---- epilogue: +b_out, column sum-of-squares over 256 rows ----
    #pragma unroll
    for (int n = 0; n < 4; ++n) {
        float local = 0.f;
        #pragma unroll
        for (int m = 0; m < 2; ++m) {
            int obase = w * 32 + m * 16 + grp * 4;
            #pragma unroll
            for (int r = 0; r < 4; ++r) {
                float f = acc2[m][n][r] + b_out[obase + r];
                acc2[m][n][r] = f;
                local += f * f;
            }
        }
        local += __shfl_xor(local, 16);
        local += __shfl_xor(local, 32);
        if (grp == 0) ss2[w][n * 16 + lr] = local;
    }
    __syncthreads();
    const float* xb2 = x + (size_t)b * C_ * N_;
    float* ob = out + (size_t)b * C_ * N_;
    #pragma unroll
    for (int n = 0; n < 4; ++n) {
        int cl = n * 16 + lr;
        int cg = col0 + cl;
        float tot = ss2[0][cl] + ss2[1][cl] + ss2[2][cl] + ss2[3][cl]
                  + ss2[4][cl] + ss2[5][cl] + ss2[6][cl] + ss2[7][cl];
        float rs = 16.f / fmaxf(sqrtf(tot), EPS_);
        #pragma unroll
        for (int m = 0; m < 2; ++m) {
            int obase = w * 32 + m * 16 + grp * 4;
            #pragma unroll
            for (int r = 0; r < 4; ++r) {
                int o = obase + r;
                ob[(size_t)o * N_ + cg] = acc2[m][n][r] * rs * g2[o] + xb2[(size_t)o * N_ + cg];
            }
        }
    }
}

extern "C" void kernel_launch(void* const* d_in, const int* in_sizes, int n_in,
                              void* d_out, int out_size, void* d_ws, size_t ws_size,
                              hipStream_t stream) {
    const float* x     = (const float*)d_in[0];
    const float* g1    = (const float*)d_in[1];
    const float* w_qkv = (const float*)d_in[2];
    const float* w_out = (const float*)d_in[3];
    const float* b_out = (const float*)d_in[4];
    const float* g2    = (const float*)d_in[5];
    float* out = (float*)d_out;
    char* ws = (char*)d_ws;

    ushort* Wp     = (ushort*)(ws + 0);          //    393216 B
    float*  ctxp   = (float*)(ws + 393216);      //   2097152 B
    float*  sums_p = (float*)(ws + 2490368);     //     65536 B
    ushort* Mm     = (ushort*)(ws + 2555904);    //   2097152 B
    ushort* xnbT   = (ushort*)(ws + 4653056);    //  33554432 B
    ushort* kv     = (ushort*)(ws + 38207488);   //  67108864 B (total 100.4 MB)

    k_prep<<<768, 256, 0, stream>>>(w_qkv, g1, Wp);
    k_xconv<<<dim3(64, 16), 256, 0, stream>>>(x, xnbT);
    k_gemm<<<dim3(32, 4, 16), 256, 0, stream>>>(Wp, xnbT, kv);
    k_ctxpart<<<dim3(128, 4), 256, 0, stream>>>(kv, ctxp, sums_p);
    k_fold<<<128, 256, 0, stream>>>(w_out, ctxp, sums_p, Mm);
    k_qfinal<<<dim3(64, 16), 512, 0, stream>>>(Wp, xnbT, Mm, b_out, g2, x, out);
}